// Round 1
// baseline (657.314 us; speedup 1.0000x reference)
//
#include <hip/hip_runtime.h>
#include <math.h>

// Problem constants: N=8192, DIM=64, K=32, ALPHA=1.0
// d_in order: node_emb[8192*64], noise[8192*8192], W1[64*64], b1[64], W2[64*64], b2[64]
// out: 8192*8192 fp32

// ---------------------------------------------------------------------------
// Kernel 1: VV[i][2k] = v1[i][k], VV[i][2k+1] = v2[i][k]
// v = gelu(emb @ W.T + b), exact-erf gelu. In-order fmaf over k (BLAS-like).
// ---------------------------------------------------------------------------
__global__ __launch_bounds__(256) void compute_vv(
    const float* __restrict__ emb, const float* __restrict__ W1,
    const float* __restrict__ b1, const float* __restrict__ W2,
    const float* __restrict__ b2, float* __restrict__ VV)
{
    __shared__ float sW[2][64 * 65];
    __shared__ float sb[2][64];
    __shared__ float semb[2][64];
    int tid = threadIdx.x;
    for (int t = tid; t < 64 * 64; t += 256) {
        int o = t >> 6, k = t & 63;
        sW[0][o * 65 + k] = W1[t];
        sW[1][o * 65 + k] = W2[t];
    }
    if (tid < 64) { sb[0][tid] = b1[tid]; sb[1][tid] = b2[tid]; }
    int i0 = blockIdx.x * 2;
    if (tid < 128) semb[tid >> 6][tid & 63] = emb[(size_t)i0 * 64 + tid];
    __syncthreads();

    int li = tid >> 7;
    int c  = tid & 127;
    int o  = c >> 1;
    int w  = c & 1;
    const float* wr = &sW[w][o * 65];
    const float* e  = &semb[li][0];
    float acc = 0.0f;
#pragma unroll
    for (int k = 0; k < 64; ++k) acc = fmaf(e[k], wr[k], acc);
    float x = acc + sb[w][o];
    double xd = (double)x;
    double g = 0.5 * xd * (1.0 + erf(xd * 0.70710678118654752440));
    VV[(size_t)(i0 + li) * 128 + c] = (float)g;
}

// ---------------------------------------------------------------------------
// Kernel 2: adj = relu(v1 v2^T - v2 v1^T), antisymmetric (upper-tri compute,
// bit-exact mirror via fmaf commutativity). Unchanged.
// ---------------------------------------------------------------------------
__global__ __launch_bounds__(256, 2) void adj_gemm_tri(
    const float* __restrict__ VV, float* __restrict__ out)
{
    int bi = blockIdx.x, bj = blockIdx.y;
    if (bj < bi) return;

    __shared__ __align__(16) float smem[16896];
    float* Ar1 = smem;
    float* Ar2 = smem + 4224;
    float* Ac1 = smem + 8448;
    float* Ac2 = smem + 12672;

    int tid  = threadIdx.x;
    int trow = tid >> 4, tcol = tid & 15;
    const int grow = bi * 128, gcol = bj * 128;

    float d1[8][8], d2[8][8];
#pragma unroll
    for (int r = 0; r < 8; ++r)
#pragma unroll
        for (int c = 0; c < 8; ++c) { d1[r][c] = 0.0f; d2[r][c] = 0.0f; }

    const float4* VV4 = (const float4*)VV;
    for (int kb = 0; kb < 2; ++kb) {
        __syncthreads();
        for (int g = tid; g < 2048; g += 256) {
            int row = g >> 4, off = g & 15;
            float4 f = VV4[(size_t)(grow + row) * 32 + kb * 16 + off];
            float4 h = VV4[(size_t)(gcol + row) * 32 + kb * 16 + off];
            int kk = off * 2;
            Ar1[kk * 132 + row] = f.x; Ar2[kk * 132 + row] = f.y;
            Ar1[(kk + 1) * 132 + row] = f.z; Ar2[(kk + 1) * 132 + row] = f.w;
            Ac1[kk * 132 + row] = h.x; Ac2[kk * 132 + row] = h.y;
            Ac1[(kk + 1) * 132 + row] = h.z; Ac2[(kk + 1) * 132 + row] = h.w;
        }
        __syncthreads();
#pragma unroll 2
        for (int k = 0; k < 32; ++k) {
            float rv1[8], rv2[8], cv1[8], cv2[8];
            *(float4*)&rv1[0] = *(const float4*)&Ar1[k * 132 + trow * 4];
            *(float4*)&rv1[4] = *(const float4*)&Ar1[k * 132 + 64 + trow * 4];
            *(float4*)&rv2[0] = *(const float4*)&Ar2[k * 132 + trow * 4];
            *(float4*)&rv2[4] = *(const float4*)&Ar2[k * 132 + 64 + trow * 4];
            *(float4*)&cv1[0] = *(const float4*)&Ac1[k * 132 + tcol * 4];
            *(float4*)&cv1[4] = *(const float4*)&Ac1[k * 132 + 64 + tcol * 4];
            *(float4*)&cv2[0] = *(const float4*)&Ac2[k * 132 + tcol * 4];
            *(float4*)&cv2[4] = *(const float4*)&Ac2[k * 132 + 64 + tcol * 4];
#pragma unroll
            for (int r = 0; r < 8; ++r)
#pragma unroll
                for (int c = 0; c < 8; ++c) {
                    d1[r][c] = fmaf(rv1[r], cv2[c], d1[r][c]);
                    d2[r][c] = fmaf(rv2[r], cv1[c], d2[r][c]);
                }
        }
    }

#pragma unroll
    for (int rr = 0; rr < 8; ++rr) {
        int r = (rr < 4) ? (trow * 4 + rr) : (64 + trow * 4 + (rr - 4));
        float4 o0, o1;
        o0.x = fmaxf(d1[rr][0] - d2[rr][0], 0.0f);
        o0.y = fmaxf(d1[rr][1] - d2[rr][1], 0.0f);
        o0.z = fmaxf(d1[rr][2] - d2[rr][2], 0.0f);
        o0.w = fmaxf(d1[rr][3] - d2[rr][3], 0.0f);
        o1.x = fmaxf(d1[rr][4] - d2[rr][4], 0.0f);
        o1.y = fmaxf(d1[rr][5] - d2[rr][5], 0.0f);
        o1.z = fmaxf(d1[rr][6] - d2[rr][6], 0.0f);
        o1.w = fmaxf(d1[rr][7] - d2[rr][7], 0.0f);
        float* op = out + (size_t)(grow + r) * 8192 + gcol;
        *(float4*)(op + tcol * 4)      = o0;
        *(float4*)(op + 64 + tcol * 4) = o1;
    }

    __syncthreads();
    float (*tT)[132] = (float(*)[132])smem;
#pragma unroll
    for (int rr = 0; rr < 8; ++rr) {
        int r = (rr < 4) ? (trow * 4 + rr) : (64 + trow * 4 + (rr - 4));
#pragma unroll
        for (int cc = 0; cc < 8; ++cc) {
            int c = (cc < 4) ? (tcol * 4 + cc) : (64 + tcol * 4 + (cc - 4));
            tT[c][r] = fmaxf(d2[rr][cc] - d1[rr][cc], 0.0f);
        }
    }
    __syncthreads();
    for (int g = tid; g < 4096; g += 256) {
        int orow_ = g >> 5, off = g & 31;
        float4 v = *(const float4*)&tT[orow_][off * 4];
        *(float4*)(out + (size_t)(gcol + orow_) * 8192 + grow + off * 4) = v;
    }
}

// ---------------------------------------------------------------------------
// Kernel 3 (v5): per-row top-32 of (adj + noise*0.01), linear-bin select.
// Round-0 restructure: the previous version held ss[32]+aa[32] (=64 regs) so
// the allocator (VGPR_Count=64) had no room for in-flight loads -> the 16
// float4 loads serialized in pairs (8 HBM round-trips/thread) and the kernel
// ran latency-bound at 35% HBM BW. Now:
//   - all 16 loads hoisted into av[8]/nv[8] (16 in flight, noise first),
//   - aa[] dropped; adj row is RE-LOADED at the end (LLC-resident: FETCH_SIZE
//     shows adj reads already hit the 256MiB L3) with the reload issued before
//     the rank phase so its latency hides under it,
//   - __launch_bounds__(256,4) pins regs <=128 -> 4 blocks/CU.
// Selection numerics identical to v4 (scores via __fadd_rn/__fmul_rn, exact
// floor bins, exact rank tie-break == lax.top_k).
// ---------------------------------------------------------------------------
#define SKIPV 0.015625f   // 2^-6
#define CAP   1024

// Exact floor bin: b such that lo + b*inv <= s < lo + (b+1)*inv, clamped 1023.
__device__ __forceinline__ int binof(float s, float lo, float scale, float inv) {
    int b = (int)((s - lo) * scale);
    if (b > 1023) b = 1023;
    if (lo + (float)b * inv > s) --b;                       // rounded up
    else if (b < 1023 && lo + (float)(b + 1) * inv <= s) ++b; // rounded down
    return b;
}

__device__ __forceinline__ void select_bin1024(
    const unsigned* __restrict__ hist, unsigned* __restrict__ chs,
    int tid, int krem, int* __restrict__ sh_bin, int* __restrict__ sh_above,
    unsigned* __restrict__ sh_total)
{
    chs[tid] = hist[tid * 4 + 0] + hist[tid * 4 + 1] +
               hist[tid * 4 + 2] + hist[tid * 4 + 3];
    __syncthreads();
    if (tid < 64) {
        unsigned g = chs[tid * 4 + 0] + chs[tid * 4 + 1] +
                     chs[tid * 4 + 2] + chs[tid * 4 + 3];
        unsigned v = g;
#pragma unroll
        for (int off = 1; off < 64; off <<= 1) {
            unsigned o = __shfl_down(v, off);
            if (tid + off < 64) v += o;
        }
        if (tid == 0) *sh_total = v;
        unsigned above = v - g;
        if (above < (unsigned)krem && (unsigned)krem <= above + g) {
            unsigned cum = above;
            int bin = -1;
            for (int c = 3; c >= 0 && bin < 0; --c) {
                unsigned cs = chs[tid * 4 + c];
                if (cum + cs >= (unsigned)krem) {
                    int cb = tid * 4 + c;
                    for (int b = 3; b >= 0; --b) {
                        unsigned h = hist[cb * 4 + b];
                        if (cum + h >= (unsigned)krem) { bin = cb * 4 + b; break; }
                        cum += h;
                    }
                } else cum += cs;
            }
            *sh_bin = bin; *sh_above = (int)cum;
        }
    }
    __syncthreads();
}

__global__ __launch_bounds__(256, 4) void topk_linear(
    const float* __restrict__ noise, float* __restrict__ out)
{
    __shared__ unsigned hist[1024];
    __shared__ unsigned chs[256];
    __shared__ float    cs[CAP];
    __shared__ int      ci[CAP];
    __shared__ unsigned flags[256];
    __shared__ int      sh_bin, sh_above;
    __shared__ unsigned sh_total, sh_cnt;

    int tid = threadIdx.x;
    int row = blockIdx.x;
    float*       orow = out   + (size_t)row * 8192;
    const float* nrow = noise + (size_t)row * 8192;
    const float4* o4 = (const float4*)orow;
    const float4* n4 = (const float4*)nrow;

    // Hoist ALL 16 loads before any consumption. Noise first: it is the HBM
    // long pole (adj hits LLC). Explicit arrays with compile-time indices
    // keep these in VGPRs (not scratch) and give 16-deep MLP per thread.
    float4 nv[8], av[8];
#pragma unroll
    for (int i = 0; i < 8; ++i) nv[i] = n4[tid + i * 256];
#pragma unroll
    for (int i = 0; i < 8; ++i) av[i] = o4[tid + i * 256];

    // LDS init overlaps the load latency (no vmcnt dependence).
    for (int i = tid; i < 1024; i += 256) hist[i] = 0u;
    flags[tid] = 0u;

    // Scores exactly as ref: __fadd_rn(adj, __fmul_rn(noise, 0.01f)).
    float ss[32];
#pragma unroll
    for (int i = 0; i < 8; ++i) {
        ss[i * 4 + 0] = __fadd_rn(av[i].x, __fmul_rn(nv[i].x, 0.01f));
        ss[i * 4 + 1] = __fadd_rn(av[i].y, __fmul_rn(nv[i].y, 0.01f));
        ss[i * 4 + 2] = __fadd_rn(av[i].z, __fmul_rn(nv[i].z, 0.01f));
        ss[i * 4 + 3] = __fadd_rn(av[i].w, __fmul_rn(nv[i].w, 0.01f));
    }
    __syncthreads();

    // Level-0 histogram: only scores >= 2^-6, bin = floor(s*128).
#pragma unroll
    for (int s = 0; s < 32; ++s) {
        if (ss[s] >= SKIPV)
            atomicAdd(&hist[binof(ss[s], 0.0f, 128.0f, 0.0078125f)], 1u);
    }
    __syncthreads();

    select_bin1024(hist, chs, tid, 32, &sh_bin, &sh_above, &sh_total);
    float Tf, lo, width;
    int krem;
    if (sh_total >= 32u) {                       // normal path (always, in practice)
        Tf    = (float)sh_bin * 0.0078125f;
        krem  = 32 - sh_above;
        lo    = Tf; width = 0.0078125f;
    } else {
        // Rare exact fallback: top-32 dips below 2^-6.
        int kr2 = 32 - (int)sh_total;
        __syncthreads();
        for (int i = tid; i < 1024; i += 256) hist[i] = 0u;
        __syncthreads();
#pragma unroll
        for (int s = 0; s < 32; ++s) {
            if (ss[s] < SKIPV)
                atomicAdd(&hist[binof(ss[s], 0.0f, 65536.0f, 1.525878906e-5f)], 1u);
        }
        __syncthreads();
        select_bin1024(hist, chs, tid, kr2, &sh_bin, &sh_above, &sh_total);
        Tf    = (float)sh_bin * 1.525878906e-5f;
        krem  = kr2 - sh_above;
        lo    = Tf; width = 1.525878906e-5f;
    }

    // Collect candidates (s >= Tf), refining if > CAP (practically never).
    int cnt;
    for (int pass = 0;; ++pass) {
        if (tid == 0) sh_cnt = 0u;
        __syncthreads();
#pragma unroll
        for (int s = 0; s < 32; ++s) {
            if (ss[s] >= Tf) {
                unsigned p = atomicAdd(&sh_cnt, 1u);
                if (p < CAP) {
                    cs[p] = ss[s];
                    ci[p] = tid * 4 + (s >> 2) * 1024 + (s & 3);
                }
            }
        }
        __syncthreads();
        cnt = (int)sh_cnt;
        if (cnt <= CAP || pass >= 2) break;
        // refine within [lo, lo+width): 1024 sub-bins
        for (int i = tid; i < 1024; i += 256) hist[i] = 0u;
        __syncthreads();
        float scale = 1024.0f / width;
        float inv   = width * 0.0009765625f;     // width/1024, dyadic
#pragma unroll
        for (int s = 0; s < 32; ++s) {
            if (ss[s] >= lo && ss[s] < lo + width)
                atomicAdd(&hist[binof(ss[s], lo, scale, inv)], 1u);
        }
        __syncthreads();
        select_bin1024(hist, chs, tid, krem, &sh_bin, &sh_above, &sh_total);
        Tf    = lo + (float)sh_bin * inv;
        krem -= sh_above;
        lo    = Tf; width = inv;
    }
    if (cnt > CAP) cnt = CAP;                    // unreachable with continuous noise

    // Re-load adj row for the masked writeback. These hit L2/LLC (written by
    // kernel 2, proven resident by FETCH_SIZE == noise only). Issued BEFORE
    // the rank phase so the cache latency hides under it. Bit-identical to
    // holding the values in registers.
    float4 rv[8];
#pragma unroll
    for (int i = 0; i < 8; ++i) rv[i] = o4[tid + i * 256];

    // Exact rank select (score desc, idx asc == lax.top_k); winners -> flags.
    for (int t = tid; t < cnt; t += 256) {
        float msv = cs[t];
        int   mi  = ci[t];
        int rank = 0;
        for (int j = 0; j < cnt; ++j) {
            float os = cs[j];
            rank += (os > msv || (os == msv && ci[j] < mi)) ? 1 : 0;
        }
        if (rank < 32) atomicOr(&flags[mi >> 5], 1u << (mi & 31));
    }
    __syncthreads();

    // Masked writeback from the reloaded registers: adj where selected, else 0.
#pragma unroll
    for (int i = 0; i < 8; ++i) {
        int j0 = 4 * (tid + i * 256);
        unsigned w = flags[j0 >> 5];
        int sh = j0 & 31;                        // j0 % 32, multiple of 4
        float4 o;
        o.x = ((w >> (sh + 0)) & 1u) ? rv[i].x : 0.0f;
        o.y = ((w >> (sh + 1)) & 1u) ? rv[i].y : 0.0f;
        o.z = ((w >> (sh + 2)) & 1u) ? rv[i].z : 0.0f;
        o.w = ((w >> (sh + 3)) & 1u) ? rv[i].w : 0.0f;
        ((float4*)orow)[tid + i * 256] = o;
    }
}

// ---------------------------------------------------------------------------
extern "C" void kernel_launch(void* const* d_in, const int* in_sizes, int n_in,
                              void* d_out, int out_size, void* d_ws, size_t ws_size,
                              hipStream_t stream) {
    (void)in_sizes; (void)n_in; (void)out_size; (void)ws_size;
    const float* emb   = (const float*)d_in[0];
    const float* noise = (const float*)d_in[1];
    const float* W1    = (const float*)d_in[2];
    const float* b1    = (const float*)d_in[3];
    const float* W2    = (const float*)d_in[4];
    const float* b2    = (const float*)d_in[5];
    float* out = (float*)d_out;
    float* VV  = (float*)d_ws;   // 8192*128 floats = 4 MiB scratch

    hipLaunchKernelGGL(compute_vv, dim3(4096), dim3(256), 0, stream,
                       emb, W1, b1, W2, b2, VV);
    hipLaunchKernelGGL(adj_gemm_tri, dim3(64, 64), dim3(256), 0, stream, VV, out);
    hipLaunchKernelGGL(topk_linear, dim3(8192), dim3(256), 0, stream, noise, out);
}